// Round 6
// baseline (26.365 us; speedup 1.0000x reference)
//
#include <hip/hip_runtime.h>

// Algebraic collapse (verified exactly, absmax 0.0 across rounds):
//   softmax over the QUERY axis => sum_q attn[b,q,k] == 1 for all (b,k), so
//   context.mean(axis=0) = mean_k V[k,b,:] = xbar @ Wv.T + bv, and
//   out[b,h] = xbar[b,h] + sum_j xbar[b,j]*Wv[h,j] + bv[h],  xbar = x.mean(0).
//   Wq, bq, Wk, bk drop out of the output entirely.
// Lessons:
//   R2: NO cooperative grid.sync on MI355X (~100us/sync). Plain boundaries.
//   R3/R4/R5: k_out variants equivalent (~1us apart). Colsum block count is
//     the lever: 1024 blocks = 38.4us total, 512 blocks = 25.2us total, with
//     identical 4KB/row/block chunk shape => concurrent-DRAM-stream count,
//     not chunk shape, drives colsum efficiency.
//   R6 experiment: SPLITS 32->16 (256 blocks, 1/CU, ROWS=64), k_reduce/k_out
//     byte-identical to R5. Tests whether the fewer-streams trend continues.

constexpr int S = 1024;
constexpr int B = 16;
constexpr int H = 1024;
constexpr int C = B * H;            // 16384 columns when x is viewed [S][B*H]
constexpr int SPLITS = 16;          // S-axis split for kernel 1 (R5 used 32)
constexpr int SCHUNK = S / SPLITS;  // 64 rows per block

// --- K1: partial column sums, float4 across columns.
// grid (C/4/256, SPLITS) = (16, 16) = 256 blocks, block 256.
__global__ void k_colsum(const float4* __restrict__ x4, float4* __restrict__ part4) {
    const int c4 = blockIdx.x * blockDim.x + threadIdx.x;   // [0, C/4)
    const int split = blockIdx.y;
    const float4* p = x4 + (size_t)split * SCHUNK * (C / 4) + c4;
    float4 a = make_float4(0.f, 0.f, 0.f, 0.f);
#pragma unroll
    for (int i = 0; i < SCHUNK; ++i) {
        float4 v = p[(size_t)i * (C / 4)];
        a.x += v.x; a.y += v.y; a.z += v.z; a.w += v.w;
    }
    part4[(size_t)split * (C / 4) + c4] = a;
}

// --- K1.5: fold SPLITS partial rows -> xsum[C] (raw sums over S, unscaled).
// grid C/256 = 64, block 256.
__global__ void k_reduce(const float* __restrict__ part, float* __restrict__ xsum) {
    const int c = blockIdx.x * blockDim.x + threadIdx.x;
    float a = 0.f;
#pragma unroll
    for (int t = 0; t < SPLITS; ++t) a += part[(size_t)t * C + c];
    xsum[c] = a;
}

// --- K2: one wave per output element (R1/R5-proven).
// out[b*H+h] = (xsum[b*H+h] + sum_j xsum[b*H+j]*Wv[h*H+j]) / S + bv[h]
// grid 4096, block 256 (4 waves/block) -> 16384 waves.
__global__ void k_out(const float* __restrict__ xsum, const float* __restrict__ Wv,
                      const float* __restrict__ bv, float* __restrict__ out) {
    const int wid = (blockIdx.x * blockDim.x + threadIdx.x) >> 6;  // [0, 16384)
    const int lane = threadIdx.x & 63;
    const int b = wid >> 10;      // [0,16)
    const int h = wid & 1023;     // [0,1024)
    const float4* xr = (const float4*)(xsum + (size_t)b * H);
    const float4* wr = (const float4*)(Wv + (size_t)h * H);
    float acc = 0.f;
#pragma unroll
    for (int it = 0; it < 4; ++it) {
        const int j4 = lane + it * 64;          // 256 float4 per row
        float4 xv = xr[j4];
        float4 wv = wr[j4];
        acc += xv.x * wv.x + xv.y * wv.y + xv.z * wv.z + xv.w * wv.w;
    }
#pragma unroll
    for (int off = 32; off > 0; off >>= 1) acc += __shfl_down(acc, off, 64);
    if (lane == 0) {
        const int c = b * H + h;
        out[c] = (xsum[c] + acc) * (1.0f / (float)S) + bv[h];
    }
}

extern "C" void kernel_launch(void* const* d_in, const int* in_sizes, int n_in,
                              void* d_out, int out_size, void* d_ws, size_t ws_size,
                              hipStream_t stream) {
    const float* x  = (const float*)d_in[0];
    // d_in[1..4] (Wq,bq,Wk,bk) are provably unused (see header).
    const float* Wv = (const float*)d_in[5];
    const float* bv = (const float*)d_in[6];
    float* out = (float*)d_out;
    float* ws  = (float*)d_ws;

    float* part = ws;                       // [SPLITS][C]  = 1 MiB
    float* xsum = ws + (size_t)SPLITS * C;  // [C]
    k_colsum<<<dim3(C / 4 / 256, SPLITS), 256, 0, stream>>>(
        (const float4*)x, (float4*)part);
    k_reduce<<<C / 256, 256, 0, stream>>>(part, xsum);
    k_out<<<16384 / 4, 256, 0, stream>>>(xsum, Wv, bv, out);
}

// Round 7
// 23.909 us; speedup vs baseline: 1.1027x; 1.1027x over previous
//
#include <hip/hip_runtime.h>

// Algebraic collapse (verified exactly, absmax 0.0 across rounds):
//   softmax over the QUERY axis => sum_q attn[b,q,k] == 1 for all (b,k), so
//   context.mean(axis=0) = mean_k V[k,b,:] = xbar @ Wv.T + bv, and
//   out[b,h] = xbar[b,h] + sum_j xbar[b,j]*Wv[h,j] + bv[h],  xbar = x.mean(0).
//   Wq, bq, Wk, bk drop out of the output entirely.
// Lessons:
//   R2: NO cooperative grid.sync on MI355X (~100us/sync). Plain boundaries.
//   R3-R6 colsum block-count scan (strided pattern, k_out held fixed):
//     1024 blk = 38.4us, 512 blk = 25.2us (BEST), 256 blk = 26.4us.
//     => colsum FROZEN at SPLITS=32 / 512 blocks (R5 shape).
//   R7: single-variable change — k_out Wv-register-reuse: one wave per
//     (h, 8 b's) instead of per (b,h). Wv L2 traffic 64->8 MiB. Summation
//     order per (b,h) unchanged => expect absmax 0.0.

constexpr int S = 1024;
constexpr int B = 16;
constexpr int H = 1024;
constexpr int C = B * H;            // 16384 columns when x is viewed [S][B*H]
constexpr int SPLITS = 32;          // S-axis split for kernel 1 (empirical best)
constexpr int SCHUNK = S / SPLITS;  // 32 rows per block

// --- K1: partial column sums, float4 across columns. (R5 byte-identical)
// grid (16, 32) = 512 blocks, block 256.
__global__ void k_colsum(const float4* __restrict__ x4, float4* __restrict__ part4) {
    const int c4 = blockIdx.x * blockDim.x + threadIdx.x;   // [0, C/4)
    const int split = blockIdx.y;
    const float4* p = x4 + (size_t)split * SCHUNK * (C / 4) + c4;
    float4 a = make_float4(0.f, 0.f, 0.f, 0.f);
#pragma unroll
    for (int i = 0; i < SCHUNK; ++i) {
        float4 v = p[(size_t)i * (C / 4)];
        a.x += v.x; a.y += v.y; a.z += v.z; a.w += v.w;
    }
    part4[(size_t)split * (C / 4) + c4] = a;
}

// --- K1.5: fold 32 partial rows -> xsum[C]. (R5 byte-identical)
__global__ void k_reduce(const float* __restrict__ part, float* __restrict__ xsum) {
    const int c = blockIdx.x * blockDim.x + threadIdx.x;
    float a = 0.f;
#pragma unroll
    for (int t = 0; t < SPLITS; ++t) a += part[(size_t)t * C + c];
    xsum[c] = a;
}

// --- K2 (NEW): one wave per (h, b-octet). 512 blocks x 256 = 2048 waves.
// Wave wid: h = wid>>1, b in [ (wid&1)*8, +8 ). Wv row held in 4 float4
// registers, reused across the 8 b's. Per-(b,h) arithmetic order identical
// to the R5 wave-per-(b,h) kernel.
__global__ void __launch_bounds__(256) k_out(const float* __restrict__ xsum,
                                             const float* __restrict__ Wv,
                                             const float* __restrict__ bv,
                                             float* __restrict__ out) {
    const int wid  = (blockIdx.x * 256 + threadIdx.x) >> 6;  // [0, 2048)
    const int lane = threadIdx.x & 63;
    const int h    = wid >> 1;           // [0, 1024)
    const int bh   = (wid & 1) * 8;      // 0 or 8

    const float4* wr = (const float4*)(Wv + (size_t)h * H);  // 256 float4/row
    const float4 w0 = wr[lane], w1 = wr[lane + 64],
                 w2 = wr[lane + 128], w3 = wr[lane + 192];
    const float bvh = bv[h];

    float acc[8];
#pragma unroll
    for (int b = 0; b < 8; ++b) {
        const float4* xr = (const float4*)(xsum + (size_t)(bh + b) * H);
        const float4 a0 = xr[lane], a1 = xr[lane + 64],
                     a2 = xr[lane + 128], a3 = xr[lane + 192];
        acc[b] = a0.x * w0.x + a0.y * w0.y + a0.z * w0.z + a0.w * w0.w
               + a1.x * w1.x + a1.y * w1.y + a1.z * w1.z + a1.w * w1.w
               + a2.x * w2.x + a2.y * w2.y + a2.z * w2.z + a2.w * w2.w
               + a3.x * w3.x + a3.y * w3.y + a3.z * w3.z + a3.w * w3.w;
    }
#pragma unroll
    for (int b = 0; b < 8; ++b) {
#pragma unroll
        for (int off = 32; off; off >>= 1) acc[b] += __shfl_down(acc[b], off, 64);
    }
    if (lane == 0) {
#pragma unroll
        for (int b = 0; b < 8; ++b) {
            const int c = (bh + b) * H + h;
            out[c] = (xsum[c] + acc[b]) * (1.0f / (float)S) + bvh;
        }
    }
}

extern "C" void kernel_launch(void* const* d_in, const int* in_sizes, int n_in,
                              void* d_out, int out_size, void* d_ws, size_t ws_size,
                              hipStream_t stream) {
    const float* x  = (const float*)d_in[0];
    // d_in[1..4] (Wq,bq,Wk,bk) are provably unused (see header).
    const float* Wv = (const float*)d_in[5];
    const float* bv = (const float*)d_in[6];
    float* out = (float*)d_out;
    float* ws  = (float*)d_ws;

    float* part = ws;                       // [SPLITS][C]  = 2 MiB
    float* xsum = ws + (size_t)SPLITS * C;  // [C]
    k_colsum<<<dim3(C / 4 / 256, SPLITS), 256, 0, stream>>>(
        (const float4*)x, (float4*)part);
    k_reduce<<<C / 256, 256, 0, stream>>>(part, xsum);
    k_out<<<512, 256, 0, stream>>>(xsum, Wv, bv, out);
}